// Round 7
// baseline (28.325 us; speedup 1.0000x reference)
//
#include <hip/hip_runtime.h>
#include <math.h>

#define NSAMP 32
#define HW 512
#define PW 128
#define NPOOL (PW * PW)                 // 16384 pooled elements / sample
#define BPS 16                          // blocks per sample
#define NBLOCKS (NSAMP * BPS)           // 512 (2 blocks / CU) — measured sweet spot
#define PPT 4                           // pooled patches per thread
#define NACC 14
#define FP_SCALE 1073741824.0           // 2^30 fixed-point scale
#define FP_INV   (1.0 / 1073741824.0)

// cells[s*NACC+k] layout: 0 bce(log2) 1 mask_cnt 2 intersection 3 label_sum
// 4 S_v 5 S_h 6 S_l 7 S_vv 8 S_hh 9 S_ll 10 S_vh 11 S_vl 12 S_hl 13 S_vhl

// full-wave (64 lane) sum via DPP on the VALU pipe; result valid in lane 63
__device__ __forceinline__ float wave_sum_dpp(float x) {
#define DPP_ADD(ctrl)                                                         \
    x += __int_as_float(__builtin_amdgcn_update_dpp(                          \
        0, __float_as_int(x), (ctrl), 0xf, 0xf, true));
    DPP_ADD(0x111)   // row_shr:1
    DPP_ADD(0x112)   // row_shr:2
    DPP_ADD(0x114)   // row_shr:4
    DPP_ADD(0x118)   // row_shr:8
    DPP_ADD(0x142)   // row_bcast:15
    DPP_ADD(0x143)   // row_bcast:31 -> lane 63 = full 64-lane sum
#undef DPP_ADD
    return x;
}

__global__ __launch_bounds__(256) void covloss_fused(
    const float* __restrict__ logits, const float* __restrict__ labels,
    const float* __restrict__ v_att,  const float* __restrict__ h_att,
    float* __restrict__ out, unsigned long long* __restrict__ ws)
{
    unsigned long long* counter = ws;        // ws[0]
    unsigned long long* cells   = ws + 8;    // 32*14 u64 cells (64B-aligned)

    const int bid   = blockIdx.x;
    const int n     = bid >> 4;              // sample
    const int local = bid & 15;              // block within sample

    const float* lg = logits + (size_t)n * HW * HW;
    const float* lb = labels + (size_t)n * HW * HW;
    const float* va = v_att + (size_t)n * NPOOL;
    const float* ha = h_att + (size_t)n * NPOOL;

    float bce = 0.f, inter = 0.f, ysum = 0.f;
    unsigned long long cnt_u = 0;            // wave-uniform via ballot (SALU)
    float S_v = 0.f, S_h = 0.f, S_l = 0.f;
    float S_vv = 0.f, S_hh = 0.f, S_ll = 0.f;
    float S_vh = 0.f, S_vl = 0.f, S_hl = 0.f, S_vhl = 0.f;

#pragma unroll
    for (int p = 0; p < PPT; ++p) {
        const int pidx = local * (PPT * 256) + p * 256 + threadIdx.x;
        const int pr = pidx >> 7;            // pooled row
        const int pc = pidx & 127;           // pooled col
        const float4* lg4 = (const float4*)(lg + (size_t)(4 * pr) * HW) + pc;
        const float4* lb4 = (const float4*)(lb + (size_t)(4 * pr) * HW) + pc;

        // hoist all 8 loads (+2 attention) before compute: max loads in flight
        float4 P[4], Y[4];
#pragma unroll
        for (int i = 0; i < 4; ++i) P[i] = lg4[i * (HW / 4)];
#pragma unroll
        for (int i = 0; i < 4; ++i) Y[i] = lb4[i * (HW / 4)];
        const float v = va[pidx];
        const float h = ha[pidx];

        float lsum = 0.f;
#pragma unroll
        for (int i = 0; i < 4; ++i) {
            const float pv[4] = {P[i].x, P[i].y, P[i].z, P[i].w};
            const float yv[4] = {Y[i].x, Y[i].y, Y[i].z, Y[i].w};
#pragma unroll
            for (int j = 0; j < 4; ++j) {
                const float pp = pv[j], y = yv[j];
                bce = fmaf(y, __log2f(pp), bce);            // ln2 folded at finalize
                bce = fmaf(1.f - y, __log2f(1.f - pp), bce);
                const bool m = pp > 0.4f;
                cnt_u += __popcll(__ballot(m));             // scalar pipe
                inter += m ? y : 0.f;
                lsum  += y;
            }
        }
        ysum += lsum;
        const float l = lsum * 0.0625f;      // 4x4 average pool value
        S_v += v;          S_h += h;          S_l += l;
        S_vv = fmaf(v, v, S_vv);  S_hh = fmaf(h, h, S_hh);  S_ll = fmaf(l, l, S_ll);
        const float vh = v * h;
        S_vh += vh;        S_vl = fmaf(v, l, S_vl);  S_hl = fmaf(h, l, S_hl);
        S_vhl = fmaf(vh, l, S_vhl);
    }

    float vals[13] = { bce, inter, ysum,
                       S_v, S_h, S_l, S_vv, S_hh, S_ll,
                       S_vh, S_vl, S_hl, S_vhl };
#pragma unroll
    for (int k = 0; k < 13; ++k) vals[k] = wave_sum_dpp(vals[k]);

    __shared__ float sh[4][NACC];
    const int lane = threadIdx.x & 63, wv = threadIdx.x >> 6;
    if (lane == 63) {
        sh[wv][0] = vals[0];
        sh[wv][1] = (float)cnt_u;            // per-wave count (<=4096, exact)
        sh[wv][2] = vals[1];
        sh[wv][3] = vals[2];
#pragma unroll
        for (int k = 3; k < 13; ++k) sh[wv][k + 1] = vals[k];
    }
    __syncthreads();

    // 14 relaxed integer atomics per block: deterministic (order-independent),
    // no cache-maintenance (atomics execute at the device-coherent point).
    if (threadIdx.x < NACC) {
        const double d = (double)(sh[0][threadIdx.x] + sh[1][threadIdx.x] +
                                  sh[2][threadIdx.x] + sh[3][threadIdx.x]);
        const long long q = __double2ll_rn(d * FP_SCALE);
        atomicAdd(&cells[n * NACC + threadIdx.x], (unsigned long long)q);
    }

    // rendezvous: wave 0 waits its own atomics' completion ack (vmcnt), then bumps
    __shared__ int lastflag;
    if (threadIdx.x == 0) {
        __builtin_amdgcn_s_waitcnt(0);       // vmcnt(0): adds reached coherent point
        const unsigned long long old = atomicAdd(counter, 1ULL);
        lastflag = (old == NBLOCKS - 1);
    }
    __syncthreads();
    if (!lastflag) return;

    // ---- finalize: exactly one block, fixed data -> deterministic ----
    const int t = threadIdx.x;
    __shared__ double acc[NSAMP][NACC];
    for (int c = t; c < NSAMP * NACC; c += 256) {
        const unsigned long long u =
            __hip_atomic_load(&cells[c], __ATOMIC_RELAXED, __HIP_MEMORY_SCOPE_AGENT);
        ((double*)acc)[c] = (double)(long long)u * FP_INV;
    }
    __syncthreads();

    __shared__ double sb[NSAMP], sd[NSAMP], sc[NSAMP];
    if (t < NSAMP) {
        const double* a = acc[t];
        const double nn = (double)NPOOL;
        const double cvv = a[7] - a[4] * a[4] / nn;
        const double chh = a[8] - a[5] * a[5] / nn;
        const double cll = a[9] - a[6] * a[6] / nn;
        const double num = a[13]
            - (a[4] * a[12] + a[5] * a[11] + a[6] * a[10]) / nn
            + 2.0 * a[4] * a[5] * a[6] / (nn * nn);
        sc[t] = num / sqrt(cvv * chh * cll);
        sd[t] = 2.0 * (a[2] + 1.0) / (a[1] + a[3] + 1.0);
        sb[t] = a[0];
    }
    __syncthreads();
    if (t == 0) {
        double bces = 0.0, ds = 0.0, cs = 0.0;
#pragma unroll
        for (int i = 0; i < NSAMP; ++i) { bces += sb[i]; ds += sd[i]; cs += sc[i]; }
        const double bceloss = -(bces * M_LN2) / ((double)NSAMP * HW * HW);
        out[0] = (float)(0.2 * bceloss + 0.3 * (1.0 - ds / NSAMP) + 0.5 * (-cs / NSAMP));
    }
}

extern "C" void kernel_launch(void* const* d_in, const int* in_sizes, int n_in,
                              void* d_out, int out_size, void* d_ws, size_t ws_size,
                              hipStream_t stream) {
    const float* logits = (const float*)d_in[0];
    const float* labels = (const float*)d_in[1];
    const float* v_att  = (const float*)d_in[2];
    const float* h_att  = (const float*)d_in[3];
    float* out = (float*)d_out;
    unsigned long long* ws = (unsigned long long*)d_ws;

    // zero counter + 32*14 cells (graph-capture legal)
    hipMemsetAsync(d_ws, 0, 8 * 8 + (size_t)NSAMP * NACC * 8, stream);
    covloss_fused<<<NBLOCKS, 256, 0, stream>>>(logits, labels, v_att, h_att, out, ws);
}

// Round 8
// 20.678 us; speedup vs baseline: 1.3698x; 1.3698x over previous
//
#include <hip/hip_runtime.h>
#include <math.h>

#define NSAMP 32
#define HW 512
#define PW 128
#define NPOOL (PW * PW)                 // 16384 pooled elements / sample
#define BPS 16                          // blocks per sample
#define NBLOCKS (NSAMP * BPS)           // 512 (2 blocks / CU) — measured sweet spot
#define PPT 4                           // pooled patches per thread
#define NACC 14

// acc layout: 0 bce(log2) 1 mask_cnt 2 intersection 3 label_sum
// 4 S_v 5 S_h 6 S_l 7 S_vv 8 S_hh 9 S_ll 10 S_vh 11 S_vl 12 S_hl 13 S_vhl
// part transposed: part[k * NBLOCKS + bid]

// full-wave (64 lane) sum via DPP on the VALU pipe; result valid in lane 63
__device__ __forceinline__ float wave_sum_dpp(float x) {
#define DPP_ADD(ctrl)                                                         \
    x += __int_as_float(__builtin_amdgcn_update_dpp(                          \
        0, __float_as_int(x), (ctrl), 0xf, 0xf, true));
    DPP_ADD(0x111)   // row_shr:1
    DPP_ADD(0x112)   // row_shr:2
    DPP_ADD(0x114)   // row_shr:4
    DPP_ADD(0x118)   // row_shr:8
    DPP_ADD(0x142)   // row_bcast:15
    DPP_ADD(0x143)   // row_bcast:31 -> lane 63 = full 64-lane sum
#undef DPP_ADD
    return x;
}

__global__ __launch_bounds__(256, 2) void covloss_main(
    const float* __restrict__ logits, const float* __restrict__ labels,
    const float* __restrict__ v_att,  const float* __restrict__ h_att,
    float* __restrict__ part)
{
    const int bid   = blockIdx.x;
    const int n     = bid >> 4;              // sample
    const int local = bid & 15;              // block within sample
    const int pbase = local * (PPT * 256);

    const float* lg = logits + (size_t)n * HW * HW;
    const float* lb = labels + (size_t)n * HW * HW;
    const float* va = v_att + (size_t)n * NPOOL;
    const float* ha = h_att + (size_t)n * NPOOL;

    float bce = 0.f, inter = 0.f, ysum = 0.f;
    unsigned long long cnt_u = 0;            // wave-uniform via ballot (SALU)
    float S_v = 0.f, S_h = 0.f, S_l = 0.f;
    float S_vv = 0.f, S_hh = 0.f, S_ll = 0.f;
    float S_vh = 0.f, S_vl = 0.f, S_hl = 0.f, S_vhl = 0.f;

    // three named prefetch buffers (all indices compile-time -> registers)
    float4 PA[4], YA[4]; float vA, hA;
    float4 PB[4], YB[4]; float vB, hB;
    float4 PC[4], YC[4]; float vC, hC;

#define LOADBUF(S, p) {                                                       \
    const int pidx = pbase + (p) * 256 + (int)threadIdx.x;                    \
    const int pr = pidx >> 7, pc = pidx & 127;                                \
    const float4* lg4 = (const float4*)(lg + (size_t)(4 * pr) * HW) + pc;     \
    const float4* lb4 = (const float4*)(lb + (size_t)(4 * pr) * HW) + pc;     \
    P##S[0] = lg4[0]; P##S[1] = lg4[HW / 4];                                  \
    P##S[2] = lg4[2 * (HW / 4)]; P##S[3] = lg4[3 * (HW / 4)];                 \
    Y##S[0] = lb4[0]; Y##S[1] = lb4[HW / 4];                                  \
    Y##S[2] = lb4[2 * (HW / 4)]; Y##S[3] = lb4[3 * (HW / 4)];                 \
    v##S = va[pidx]; h##S = ha[pidx]; }

#define COMPUTE(S) {                                                          \
    float lsum = 0.f;                                                         \
    _Pragma("unroll")                                                         \
    for (int i = 0; i < 4; ++i) {                                             \
        const float pv[4] = {P##S[i].x, P##S[i].y, P##S[i].z, P##S[i].w};     \
        const float yv[4] = {Y##S[i].x, Y##S[i].y, Y##S[i].z, Y##S[i].w};     \
        _Pragma("unroll")                                                     \
        for (int j = 0; j < 4; ++j) {                                         \
            const float pp = pv[j], y = yv[j];                                \
            bce = fmaf(y, __log2f(pp), bce);                                  \
            bce = fmaf(1.f - y, __log2f(1.f - pp), bce);                      \
            const bool m = pp > 0.4f;                                         \
            cnt_u += __popcll(__ballot(m));                                   \
            inter += m ? y : 0.f;                                             \
            lsum  += y;                                                       \
        }                                                                     \
    }                                                                         \
    ysum += lsum;                                                             \
    const float l = lsum * 0.0625f;                                           \
    const float v = v##S, h = h##S;                                           \
    S_v += v; S_h += h; S_l += l;                                             \
    S_vv = fmaf(v, v, S_vv); S_hh = fmaf(h, h, S_hh); S_ll = fmaf(l, l, S_ll);\
    const float vh = v * h;                                                   \
    S_vh += vh; S_vl = fmaf(v, l, S_vl); S_hl = fmaf(h, l, S_hl);             \
    S_vhl = fmaf(vh, l, S_vhl); }

    // depth-2 software pipeline: loads for p+1, p+2 in flight during compute(p)
    LOADBUF(A, 0)
    LOADBUF(B, 1)
    LOADBUF(C, 2)
    COMPUTE(A)
    LOADBUF(A, 3)
    COMPUTE(B)
    COMPUTE(C)
    COMPUTE(A)

#undef LOADBUF
#undef COMPUTE

    // 13 lane-varying accumulators; cnt_u is wave-uniform
    float vals[13] = { bce, inter, ysum,
                       S_v, S_h, S_l, S_vv, S_hh, S_ll,
                       S_vh, S_vl, S_hl, S_vhl };
#pragma unroll
    for (int k = 0; k < 13; ++k) vals[k] = wave_sum_dpp(vals[k]);

    __shared__ float sh[4][NACC];
    const int lane = threadIdx.x & 63, wv = threadIdx.x >> 6;
    if (lane == 63) {
        sh[wv][0] = vals[0];
        sh[wv][1] = (float)cnt_u;
        sh[wv][2] = vals[1];
        sh[wv][3] = vals[2];
#pragma unroll
        for (int k = 3; k < 13; ++k) sh[wv][k + 1] = vals[k];
    }
    __syncthreads();
    if (threadIdx.x < NACC) {
        part[(size_t)threadIdx.x * NBLOCKS + bid] =
            sh[0][threadIdx.x] + sh[1][threadIdx.x] + sh[2][threadIdx.x] + sh[3][threadIdx.x];
    }
}

__global__ __launch_bounds__(256) void covloss_finalize(
    const float* __restrict__ part, float* __restrict__ out)
{
    const int t = threadIdx.x;
    __shared__ double acc[NSAMP][NACC];

    // 448 (sample, moment) pairs; each = sum of BPS=16 contiguous floats
    for (int pair = t; pair < NSAMP * NACC; pair += 256) {
        const int s = pair / NACC, k = pair % NACC;
        const float4* p = (const float4*)(part + (size_t)k * NBLOCKS + s * BPS);
        double a = 0.0;
#pragma unroll
        for (int i = 0; i < 4; ++i) {
            const float4 q = p[i];
            a += (double)q.x + (double)q.y + (double)q.z + (double)q.w;
        }
        acc[s][k] = a;
    }
    __syncthreads();

    __shared__ double sb[NSAMP], sd[NSAMP], sc[NSAMP];
    if (t < NSAMP) {
        const double* a = acc[t];
        const double nn = (double)NPOOL;
        const double cvv = a[7] - a[4] * a[4] / nn;
        const double chh = a[8] - a[5] * a[5] / nn;
        const double cll = a[9] - a[6] * a[6] / nn;
        const double num = a[13]
            - (a[4] * a[12] + a[5] * a[11] + a[6] * a[10]) / nn
            + 2.0 * a[4] * a[5] * a[6] / (nn * nn);
        sc[t] = num / sqrt(cvv * chh * cll);
        sd[t] = 2.0 * (a[2] + 1.0) / (a[1] + a[3] + 1.0);
        sb[t] = a[0];
    }
    __syncthreads();
    if (t == 0) {
        double bces = 0.0, ds = 0.0, cs = 0.0;
#pragma unroll
        for (int i = 0; i < NSAMP; ++i) { bces += sb[i]; ds += sd[i]; cs += sc[i]; }
        const double bceloss = -(bces * M_LN2) / ((double)NSAMP * HW * HW);
        out[0] = (float)(0.2 * bceloss + 0.3 * (1.0 - ds / NSAMP) + 0.5 * (-cs / NSAMP));
    }
}

extern "C" void kernel_launch(void* const* d_in, const int* in_sizes, int n_in,
                              void* d_out, int out_size, void* d_ws, size_t ws_size,
                              hipStream_t stream) {
    const float* logits = (const float*)d_in[0];
    const float* labels = (const float*)d_in[1];
    const float* v_att  = (const float*)d_in[2];
    const float* h_att  = (const float*)d_in[3];
    float* out  = (float*)d_out;
    float* part = (float*)d_ws;   // NACC * NBLOCKS floats = 28 KB

    covloss_main<<<NBLOCKS, 256, 0, stream>>>(logits, labels, v_att, h_att, part);
    covloss_finalize<<<1, 256, 0, stream>>>(part, out);
}